// Round 1
// baseline (804.150 us; speedup 1.0000x reference)
//
#include <hip/hip_runtime.h>
#include <hip/hip_bf16.h>

#define BB 4
#define TT 2048
#define CC 1024
#define HH 16
#define DD 64

typedef __bf16 bf16x8 __attribute__((ext_vector_type(8)));
typedef float f32x4 __attribute__((ext_vector_type(4)));
typedef unsigned int u32x4 __attribute__((ext_vector_type(4)));
typedef unsigned short u16x8 __attribute__((ext_vector_type(8)));
typedef unsigned short u16x4 __attribute__((ext_vector_type(4)));

__device__ __forceinline__ unsigned short f2bf(float f) {
  unsigned int u = __builtin_bit_cast(unsigned int, f);
  u += 0x7fff + ((u >> 16) & 1);   // RNE
  return (unsigned short)(u >> 16);
}

__device__ __forceinline__ bf16x8 lds_load8(const unsigned short* p) {
  u32x4 t = *(const u32x4*)p;
  return __builtin_bit_cast(bf16x8, t);
}

// ---------------- Kernel 1: qkv = x @ W_attn + b_attn (+ head bias), scaled Q ----
// M=8192, K=1024, N=3072. Tile 128x128, BK=32. Output bf16 [B,H,T,D] per section.
__global__ __launch_bounds__(256) void qkv_gemm(
    const float* __restrict__ x, const float* __restrict__ W,
    const float* __restrict__ b_attn, const float* __restrict__ bQ,
    const float* __restrict__ bK, const float* __restrict__ bV,
    unsigned short* __restrict__ Qb, unsigned short* __restrict__ Kb,
    unsigned short* __restrict__ Vb)
{
  __shared__ unsigned short Al[128 * 40];   // [m][k] pad 40
  __shared__ unsigned short Bl[128 * 40];   // [n][k] (transposed) pad 40
  const int tid  = threadIdx.x;
  const int w    = tid >> 6, lane = tid & 63;
  const int l16  = lane & 15, quad = lane >> 4;
  const int nblk = blockIdx.x % 24, mblk = blockIdx.x / 24;  // n fastest: L2 reuse of A rows
  const int m0 = mblk * 128, n0 = nblk * 128;
  const int wm = (w & 1) * 64, wn = (w >> 1) * 64;

  f32x4 acc[4][4] = {};

  for (int kb = 0; kb < 1024; kb += 32) {
    __syncthreads();
    // stage A: 128x32 fp32 -> bf16
#pragma unroll
    for (int i = 0; i < 4; ++i) {
      int e = (i * 256 + tid) * 4;
      int m = e >> 5, k = e & 31;
      f32x4 xa = *(const f32x4*)(x + (size_t)(m0 + m) * 1024 + kb + k);
      u16x4 pk;
      pk[0] = f2bf(xa[0]); pk[1] = f2bf(xa[1]);
      pk[2] = f2bf(xa[2]); pk[3] = f2bf(xa[3]);
      *(u16x4*)(&Al[m * 40 + k]) = pk;
    }
    // stage B transposed: 32x128 fp32 -> bf16 at [n][k]
#pragma unroll
    for (int i = 0; i < 4; ++i) {
      int e = (i * 256 + tid) * 4;
      int kk = e >> 7, n = e & 127;
      f32x4 wb = *(const f32x4*)(W + (size_t)(kb + kk) * 3072 + n0 + n);
      Bl[(n + 0) * 40 + kk] = f2bf(wb[0]);
      Bl[(n + 1) * 40 + kk] = f2bf(wb[1]);
      Bl[(n + 2) * 40 + kk] = f2bf(wb[2]);
      Bl[(n + 3) * 40 + kk] = f2bf(wb[3]);
    }
    __syncthreads();
    bf16x8 af[4], bfr[4];
#pragma unroll
    for (int mi = 0; mi < 4; ++mi)
      af[mi] = lds_load8(&Al[(wm + mi * 16 + l16) * 40 + quad * 8]);
#pragma unroll
    for (int ni = 0; ni < 4; ++ni)
      bfr[ni] = lds_load8(&Bl[(wn + ni * 16 + l16) * 40 + quad * 8]);
#pragma unroll
    for (int mi = 0; mi < 4; ++mi)
#pragma unroll
      for (int ni = 0; ni < 4; ++ni)
        acc[mi][ni] = __builtin_amdgcn_mfma_f32_16x16x32_bf16(
            af[mi], bfr[ni], acc[mi][ni], 0, 0, 0);
  }

  // epilogue: bias, per-head bias, scale Q by 1/8, scatter to [B,H,T,D] bf16
  unsigned short* dst[4];
  float biasv[4], sc[4];
#pragma unroll
  for (int ni = 0; ni < 4; ++ni) {
    int col = n0 + wn + ni * 16 + l16;
    int sec = col >> 10, cc = col & 1023;
    unsigned short* base = (sec == 0) ? Qb : (sec == 1 ? Kb : Vb);
    const float* hb = (sec == 0) ? bQ : (sec == 1 ? bK : bV);
    biasv[ni] = b_attn[col] + hb[cc];
    sc[ni] = (sec == 0) ? 0.125f : 1.0f;   // 1/sqrt(64), exact in bf16
    dst[ni] = base + (size_t)(cc >> 6) * (TT * DD) + (cc & 63);
  }
#pragma unroll
  for (int mi = 0; mi < 4; ++mi)
#pragma unroll
    for (int r = 0; r < 4; ++r) {
      int m = m0 + wm + mi * 16 + quad * 4 + r;
      int bidx = m >> 11, t = m & 2047;
      size_t ro = (size_t)bidx * (HH * TT * DD) + (size_t)t * DD;
#pragma unroll
      for (int ni = 0; ni < 4; ++ni)
        dst[ni][ro] = f2bf((acc[mi][ni][r] + biasv[ni]) * sc[ni]);
    }
}

// ---------------- Kernel 2: causal flash attention ----------------
// grid = B*H*16 blocks; block = 256 threads = 4 waves x 32 q-rows; K-tiles of 32.
__global__ __launch_bounds__(256) void attn_kernel(
    const unsigned short* __restrict__ Qb, const unsigned short* __restrict__ Kb,
    const unsigned short* __restrict__ Vb, unsigned short* __restrict__ Yb)
{
  __shared__ unsigned short Kl[32 * 72];    // [key][d] pad 72
  __shared__ unsigned short Vt[64 * 40];    // [d][key] pad 40
  __shared__ unsigned short Pl[128 * 40];   // per-wave 32 rows, [row][key] pad 40
  const int tid = threadIdx.x;
  const int w = tid >> 6, lane = tid & 63;
  const int l16 = lane & 15, quad = lane >> 4;
  const int qt = blockIdx.x & 15, bh = blockIdx.x >> 4;
  const int b = bh >> 4, h = bh & 15;
  const int q0 = qt * 128, qw = q0 + w * 32;

  const unsigned short* Qg = Qb + (size_t)bh * TT * DD;
  const unsigned short* Kg = Kb + (size_t)bh * TT * DD;
  const unsigned short* Vg = Vb + (size_t)bh * TT * DD;

  // Q fragments (already pre-scaled by 1/8) held in registers for whole kernel
  bf16x8 qf[2][2];
#pragma unroll
  for (int mi = 0; mi < 2; ++mi)
#pragma unroll
    for (int dk = 0; dk < 2; ++dk) {
      u32x4 t = *(const u32x4*)(Qg + (size_t)(qw + mi * 16 + l16) * 64 + dk * 32 + quad * 8);
      qf[mi][dk] = __builtin_bit_cast(bf16x8, t);
    }

  f32x4 accO[2][4] = {};
  float mrun[2][4], lrun[2][4];
#pragma unroll
  for (int mi = 0; mi < 2; ++mi)
#pragma unroll
    for (int r = 0; r < 4; ++r) { mrun[mi][r] = -1e30f; lrun[mi][r] = 0.f; }

  const int kend = q0 + 128;
  for (int k0 = 0; k0 < kend; k0 += 32) {
    __syncthreads();
    {
      int key = tid >> 3, dseg = (tid & 7) * 8;
      u32x4 kv = *(const u32x4*)(Kg + (size_t)(k0 + key) * 64 + dseg);
      *(u32x4*)(&Kl[key * 72 + dseg]) = kv;
      u32x4 vv = *(const u32x4*)(Vg + (size_t)(k0 + key) * 64 + dseg);
      u16x8 v8 = __builtin_bit_cast(u16x8, vv);
#pragma unroll
      for (int j = 0; j < 8; ++j) Vt[(dseg + j) * 40 + key] = v8[j];
    }
    __syncthreads();
    if (k0 > qw + 31) continue;   // wave-uniform skip; barrier counts stay matched

    // S = Q K^T  (16 q x 16 k tiles; 2 d-chunks)
    bf16x8 kf[2][2];
#pragma unroll
    for (int ni = 0; ni < 2; ++ni)
#pragma unroll
      for (int dk = 0; dk < 2; ++dk)
        kf[ni][dk] = lds_load8(&Kl[(ni * 16 + l16) * 72 + dk * 32 + quad * 8]);
    f32x4 accS[2][2] = {};
#pragma unroll
    for (int mi = 0; mi < 2; ++mi)
#pragma unroll
      for (int ni = 0; ni < 2; ++ni)
#pragma unroll
        for (int dk = 0; dk < 2; ++dk)
          accS[mi][ni] = __builtin_amdgcn_mfma_f32_16x16x32_bf16(
              qf[mi][dk], kf[ni][dk], accS[mi][ni], 0, 0, 0);

    // online softmax; P -> per-wave LDS (C-layout -> A-layout transform)
#pragma unroll
    for (int mi = 0; mi < 2; ++mi) {
#pragma unroll
      for (int r = 0; r < 4; ++r) {
        int qrow = qw + mi * 16 + quad * 4 + r;
        float s0 = accS[mi][0][r];
        float s1 = accS[mi][1][r];
        if (k0 + l16 > qrow)      s0 = -1e30f;
        if (k0 + 16 + l16 > qrow) s1 = -1e30f;
        float mx = fmaxf(s0, s1);
#pragma unroll
        for (int off = 1; off < 16; off <<= 1)
          mx = fmaxf(mx, __shfl_xor(mx, off, 64));
        float mnew = fmaxf(mrun[mi][r], mx);
        float alpha = exp2f((mrun[mi][r] - mnew) * 1.44269504f);
        mrun[mi][r] = mnew;
        float p0 = exp2f((s0 - mnew) * 1.44269504f);
        float p1 = exp2f((s1 - mnew) * 1.44269504f);
        float rs = p0 + p1;
#pragma unroll
        for (int off = 1; off < 16; off <<= 1)
          rs += __shfl_xor(rs, off, 64);
        lrun[mi][r] = lrun[mi][r] * alpha + rs;
#pragma unroll
        for (int dn = 0; dn < 4; ++dn) accO[mi][dn][r] *= alpha;
        int prow = w * 32 + mi * 16 + quad * 4 + r;
        Pl[prow * 40 + l16]      = f2bf(p0);
        Pl[prow * 40 + 16 + l16] = f2bf(p1);
      }
    }

    // O += P V
    bf16x8 vf[4];
#pragma unroll
    for (int dn = 0; dn < 4; ++dn)
      vf[dn] = lds_load8(&Vt[(dn * 16 + l16) * 40 + quad * 8]);
#pragma unroll
    for (int mi = 0; mi < 2; ++mi) {
      bf16x8 pf = lds_load8(&Pl[(w * 32 + mi * 16 + l16) * 40 + quad * 8]);
#pragma unroll
      for (int dn = 0; dn < 4; ++dn)
        accO[mi][dn] = __builtin_amdgcn_mfma_f32_16x16x32_bf16(
            pf, vf[dn], accO[mi][dn], 0, 0, 0);
    }
  }

  // epilogue: O/l -> Yb [B,T,C] bf16 (col = h*64+d)
#pragma unroll
  for (int mi = 0; mi < 2; ++mi)
#pragma unroll
    for (int r = 0; r < 4; ++r) {
      int q = qw + mi * 16 + quad * 4 + r;
      float inv = 1.0f / lrun[mi][r];
      size_t base = ((size_t)b * TT + q) * CC + h * DD;
#pragma unroll
      for (int dn = 0; dn < 4; ++dn)
        Yb[base + dn * 16 + l16] = f2bf(accO[mi][dn][r] * inv);
    }
}

// ---------------- Kernel 3: out = y @ W_proj + b_proj (fp32 out) ----------------
__global__ __launch_bounds__(256) void proj_gemm(
    const unsigned short* __restrict__ Yb, const float* __restrict__ W,
    const float* __restrict__ bp, float* __restrict__ out)
{
  __shared__ unsigned short Al[128 * 40];
  __shared__ unsigned short Bl[128 * 40];
  const int tid = threadIdx.x;
  const int w = tid >> 6, lane = tid & 63;
  const int l16 = lane & 15, quad = lane >> 4;
  const int nblk = blockIdx.x & 7, mblk = blockIdx.x >> 3;
  const int m0 = mblk * 128, n0 = nblk * 128;
  const int wm = (w & 1) * 64, wn = (w >> 1) * 64;

  f32x4 acc[4][4] = {};

  for (int kb = 0; kb < 1024; kb += 32) {
    __syncthreads();
#pragma unroll
    for (int i = 0; i < 2; ++i) {
      int e = (i * 256 + tid) * 8;
      int m = e >> 5, k = e & 31;
      u32x4 a = *(const u32x4*)(Yb + (size_t)(m0 + m) * 1024 + kb + k);
      *(u32x4*)(&Al[m * 40 + k]) = a;
    }
#pragma unroll
    for (int i = 0; i < 4; ++i) {
      int e = (i * 256 + tid) * 4;
      int kk = e >> 7, n = e & 127;
      f32x4 wb = *(const f32x4*)(W + (size_t)(kb + kk) * 1024 + n0 + n);
      Bl[(n + 0) * 40 + kk] = f2bf(wb[0]);
      Bl[(n + 1) * 40 + kk] = f2bf(wb[1]);
      Bl[(n + 2) * 40 + kk] = f2bf(wb[2]);
      Bl[(n + 3) * 40 + kk] = f2bf(wb[3]);
    }
    __syncthreads();
    bf16x8 af[4], bfr[4];
#pragma unroll
    for (int mi = 0; mi < 4; ++mi)
      af[mi] = lds_load8(&Al[(wm + mi * 16 + l16) * 40 + quad * 8]);
#pragma unroll
    for (int ni = 0; ni < 4; ++ni)
      bfr[ni] = lds_load8(&Bl[(wn + ni * 16 + l16) * 40 + quad * 8]);
#pragma unroll
    for (int mi = 0; mi < 4; ++mi)
#pragma unroll
      for (int ni = 0; ni < 4; ++ni)
        acc[mi][ni] = __builtin_amdgcn_mfma_f32_16x16x32_bf16(
            af[mi], bfr[ni], acc[mi][ni], 0, 0, 0);
  }

#pragma unroll
  for (int mi = 0; mi < 4; ++mi)
#pragma unroll
    for (int r = 0; r < 4; ++r) {
      int m = m0 + wm + mi * 16 + quad * 4 + r;
#pragma unroll
      for (int ni = 0; ni < 4; ++ni) {
        int c = n0 + wn + ni * 16 + l16;
        out[(size_t)m * 1024 + c] = acc[mi][ni][r] + bp[c];
      }
    }
}

extern "C" void kernel_launch(void* const* d_in, const int* in_sizes, int n_in,
                              void* d_out, int out_size, void* d_ws, size_t ws_size,
                              hipStream_t stream) {
  const float* x      = (const float*)d_in[0];
  const float* W_attn = (const float*)d_in[1];
  const float* b_attn = (const float*)d_in[2];
  const float* W_proj = (const float*)d_in[3];
  const float* b_proj = (const float*)d_in[4];
  const float* bQ     = (const float*)d_in[5];
  const float* bK     = (const float*)d_in[6];
  const float* bV     = (const float*)d_in[7];
  float* out = (float*)d_out;

  const size_t per = (size_t)BB * HH * TT * DD;   // 8.4M elems
  unsigned short* Qb = (unsigned short*)d_ws;
  unsigned short* Kb = Qb + per;
  unsigned short* Vb = Kb + per;
  unsigned short* Yb = Vb + per;

  qkv_gemm<<<dim3(64 * 24), dim3(256), 0, stream>>>(x, W_attn, b_attn, bQ, bK, bV,
                                                    Qb, Kb, Vb);
  attn_kernel<<<dim3(64 * 16), dim3(256), 0, stream>>>(Qb, Kb, Vb, Yb);
  proj_gemm<<<dim3(64 * 8), dim3(256), 0, stream>>>(Yb, W_proj, b_proj, out);
}

// Round 2
// 330.505 us; speedup vs baseline: 2.4331x; 2.4331x over previous
//
#include <hip/hip_runtime.h>
#include <hip/hip_bf16.h>

#define BB 4
#define TT 2048
#define CC 1024
#define HH 16
#define DD 64

typedef __bf16 bf16x8 __attribute__((ext_vector_type(8)));
typedef float f32x4 __attribute__((ext_vector_type(4)));
typedef unsigned int u32x4 __attribute__((ext_vector_type(4)));
typedef unsigned short u16x8 __attribute__((ext_vector_type(8)));
typedef unsigned short u16x4 __attribute__((ext_vector_type(4)));
typedef unsigned int u32;

__device__ __forceinline__ unsigned short f2bf(float f) {
  u32 u = __builtin_bit_cast(u32, f);
  u += 0x7fff + ((u >> 16) & 1);   // RNE
  return (unsigned short)(u >> 16);
}

__device__ __forceinline__ bf16x8 lds_load8(const unsigned short* p) {
  u32x4 t = *(const u32x4*)p;
  return __builtin_bit_cast(bf16x8, t);
}

// async 16B global->LDS (dest = wave-uniform base + lane*16)
__device__ __forceinline__ void g2l16(const unsigned short* g, unsigned short* l) {
  __builtin_amdgcn_global_load_lds(
      (const __attribute__((address_space(1))) u32*)g,
      (__attribute__((address_space(3))) u32*)l, 16, 0, 0);
}

// ---------------- prep: x fp32 -> bf16 ----------------
__global__ __launch_bounds__(256) void xcast(const float* __restrict__ x,
                                             unsigned short* __restrict__ xb) {
  int i = (blockIdx.x * 256 + threadIdx.x) * 8;
  f32x4 a = *(const f32x4*)(x + i);
  f32x4 b = *(const f32x4*)(x + i + 4);
  u16x8 o;
  o[0] = f2bf(a[0]); o[1] = f2bf(a[1]); o[2] = f2bf(a[2]); o[3] = f2bf(a[3]);
  o[4] = f2bf(b[0]); o[5] = f2bf(b[1]); o[6] = f2bf(b[2]); o[7] = f2bf(b[3]);
  *(u16x8*)(xb + i) = o;
}

// ---------------- prep: W [K=1024][N] fp32 -> Wt [N][1024] bf16 ----------------
__global__ __launch_bounds__(256) void wtrans(const float* __restrict__ W,
                                              unsigned short* __restrict__ Wt, int N) {
  __shared__ unsigned short T[64 * 68];
  const int tid = threadIdx.x;
  const int n0 = blockIdx.x * 64, k0 = blockIdx.y * 64;
#pragma unroll
  for (int it = 0; it < 4; ++it) {
    int idx = it * 256 + tid;
    int kk = idx >> 4, nn = (idx & 15) * 4;
    f32x4 v = *(const f32x4*)(W + (size_t)(k0 + kk) * N + n0 + nn);
    u16x4 p;
    p[0] = f2bf(v[0]); p[1] = f2bf(v[1]); p[2] = f2bf(v[2]); p[3] = f2bf(v[3]);
    *(u16x4*)(&T[kk * 68 + nn]) = p;
  }
  __syncthreads();
#pragma unroll
  for (int it = 0; it < 4; ++it) {
    int idx = it * 256 + tid;
    int nn = idx >> 4, kc = (idx & 15) * 4;
    u16x4 o;
    o[0] = T[(kc + 0) * 68 + nn];
    o[1] = T[(kc + 1) * 68 + nn];
    o[2] = T[(kc + 2) * 68 + nn];
    o[3] = T[(kc + 3) * 68 + nn];
    *(u16x4*)(Wt + (size_t)(n0 + nn) * 1024 + k0 + kc) = o;
  }
}

// ---------------- qkv = x @ W_attn + biases; Q pre-scaled by 0.125*log2(e) ----
// m97-style: all-bf16 inputs, global_load_lds(16B) staging, unpadded LDS tiles.
__global__ __launch_bounds__(256) void qkv_gemm(
    const unsigned short* __restrict__ xb, const unsigned short* __restrict__ Wt,
    const float* __restrict__ b_attn, const float* __restrict__ bQ,
    const float* __restrict__ bK, const float* __restrict__ bV,
    unsigned short* __restrict__ Qb, unsigned short* __restrict__ Kb,
    unsigned short* __restrict__ Vb)
{
  __shared__ unsigned short Al[128 * 32];
  __shared__ unsigned short Bl[128 * 32];
  const int tid = threadIdx.x;
  const int w = tid >> 6, lane = tid & 63;
  const int l16 = lane & 15, quad = lane >> 4;
  const int nblk = blockIdx.x % 24, mblk = blockIdx.x / 24;
  const int m0 = mblk * 128, n0 = nblk * 128;
  const int wm = (w & 1) * 64, wn = (w >> 1) * 64;

  const unsigned short* ga = xb + (size_t)(m0 + w * 16 + (lane >> 2)) * 1024 + (lane & 3) * 8;
  const unsigned short* gb = Wt + (size_t)(n0 + w * 16 + (lane >> 2)) * 1024 + (lane & 3) * 8;
  unsigned short* la = &Al[w * 512];
  unsigned short* lb = &Bl[w * 512];

  f32x4 acc[4][4] = {};

  for (int kb = 0; kb < 1024; kb += 32) {
    __syncthreads();
    g2l16(ga + kb, la);
    g2l16(ga + kb + 65536, la + 2048);   // +64 rows
    g2l16(gb + kb, lb);
    g2l16(gb + kb + 65536, lb + 2048);
    __syncthreads();
    bf16x8 af[4], bfr[4];
#pragma unroll
    for (int mi = 0; mi < 4; ++mi)
      af[mi] = lds_load8(&Al[(wm + mi * 16 + l16) * 32 + quad * 8]);
#pragma unroll
    for (int ni = 0; ni < 4; ++ni)
      bfr[ni] = lds_load8(&Bl[(wn + ni * 16 + l16) * 32 + quad * 8]);
#pragma unroll
    for (int mi = 0; mi < 4; ++mi)
#pragma unroll
      for (int ni = 0; ni < 4; ++ni)
        acc[mi][ni] = __builtin_amdgcn_mfma_f32_16x16x32_bf16(
            af[mi], bfr[ni], acc[mi][ni], 0, 0, 0);
  }

  unsigned short* dst[4];
  float biasv[4], sc[4];
#pragma unroll
  for (int ni = 0; ni < 4; ++ni) {
    int col = n0 + wn + ni * 16 + l16;
    int sec = col >> 10, cc = col & 1023;
    unsigned short* base = (sec == 0) ? Qb : (sec == 1 ? Kb : Vb);
    const float* hb = (sec == 0) ? bQ : (sec == 1 ? bK : bV);
    biasv[ni] = b_attn[col] + hb[cc];
    sc[ni] = (sec == 0) ? 0.125f * 1.44269504f : 1.0f;  // fold log2(e) into Q
    dst[ni] = base + (size_t)(cc >> 6) * (TT * DD) + (cc & 63);
  }
#pragma unroll
  for (int mi = 0; mi < 4; ++mi)
#pragma unroll
    for (int r = 0; r < 4; ++r) {
      int m = m0 + wm + mi * 16 + quad * 4 + r;
      int bidx = m >> 11, t = m & 2047;
      size_t ro = (size_t)bidx * (HH * TT * DD) + (size_t)t * DD;
#pragma unroll
      for (int ni = 0; ni < 4; ++ni)
        dst[ni][ro] = f2bf((acc[mi][ni][r] + biasv[ni]) * sc[ni]);
    }
}

// ---------------- causal flash attention ----------------
// block = 4 waves; wave owns 16 q-rows (64/block); BK=64.
// Kl: global_load_lds with global-side chunk-XOR swizzle (phys = logical ^ (key&7)).
// Vt: in-LDS transpose [d][key], chunk-XOR by (d&7) -> conflict-free writes+reads.
__global__ __launch_bounds__(256) void attn_kernel(
    const unsigned short* __restrict__ Qb, const unsigned short* __restrict__ Kb,
    const unsigned short* __restrict__ Vb, unsigned short* __restrict__ Yb)
{
  __shared__ unsigned short Kl[64 * 64];
  __shared__ unsigned short Vt[64 * 64];
  __shared__ unsigned short Pl[4 * 16 * 72];
  const int tid = threadIdx.x;
  const int w = tid >> 6, lane = tid & 63;
  const int l16 = lane & 15, quad = lane >> 4;
  const int qt = 31 - (blockIdx.x >> 6);   // longest blocks dispatched first (LPT)
  const int bh = blockIdx.x & 63;          // bh mod 8 fixed per XCD -> K/V L2 locality
  const int b = bh >> 4, h = bh & 15;
  const int q0 = qt * 64, qw = q0 + w * 16;

  const unsigned short* Qg = Qb + (size_t)bh * TT * DD;
  const unsigned short* Kg = Kb + (size_t)bh * TT * DD;
  const unsigned short* Vg = Vb + (size_t)bh * TT * DD;

  // Q fragments (pre-scaled by 0.125*log2e), held for whole kernel
  bf16x8 qf[2];
#pragma unroll
  for (int dk = 0; dk < 2; ++dk) {
    u32x4 t = *(const u32x4*)(Qg + (size_t)(qw + l16) * 64 + dk * 32 + quad * 8);
    qf[dk] = __builtin_bit_cast(bf16x8, t);
  }

  f32x4 accO[4] = {};
  float mrun[4], lrun[4];
#pragma unroll
  for (int r = 0; r < 4; ++r) { mrun[r] = -3e38f; lrun[r] = 0.f; }

  // K staging constants: lane L -> row r*32 + w*8 + L/8, phys chunk L%8
  const int krow = w * 8 + (lane >> 3);
  const int kphys = lane & 7;
  unsigned short* klw = &Kl[w * 512];

  for (int k0 = 0; k0 <= q0; k0 += 64) {
    __syncthreads();
    // K: async 16B, global chunk = phys ^ (tile_row & 7)
    g2l16(Kg + (size_t)(k0 + krow) * 64 + (kphys ^ (lane >> 3)) * 8, klw);
    g2l16(Kg + (size_t)(k0 + 32 + krow) * 64 + (kphys ^ (lane >> 3)) * 8, klw + 2048);
    // V: load rows, transpose into Vt[d][key] with chunk-XOR by (d&7)
#pragma unroll
    for (int it = 0; it < 2; ++it) {
      int dbase = w * 16 + it * 8;
      u32x4 vv = *(const u32x4*)(Vg + (size_t)(k0 + lane) * 64 + dbase);
      u16x8 v8 = __builtin_bit_cast(u16x8, vv);
#pragma unroll
      for (int j = 0; j < 8; ++j)
        Vt[(dbase + j) * 64 + (((lane >> 3) ^ j) * 8) + (lane & 7)] = v8[j];
    }
    __syncthreads();

    // S = Q K^T
    f32x4 accS[4] = {};
#pragma unroll
    for (int ni = 0; ni < 4; ++ni)
#pragma unroll
      for (int dk = 0; dk < 2; ++dk) {
        bf16x8 kf = lds_load8(
            &Kl[(ni * 16 + l16) * 64 + (((dk * 4 + quad) ^ (l16 & 7)) * 8)]);
        accS[ni] = __builtin_amdgcn_mfma_f32_16x16x32_bf16(qf[dk], kf, accS[ni], 0, 0, 0);
      }

    const bool lastTile = (k0 == q0);
#pragma unroll
    for (int r = 0; r < 4; ++r) {
      int qrow = qw + quad * 4 + r;
      float s0 = accS[0][r], s1 = accS[1][r], s2 = accS[2][r], s3 = accS[3][r];
      if (lastTile) {           // masking only needed on the diagonal tile
        if (k0 + 0  + l16 > qrow) s0 = -3e38f;
        if (k0 + 16 + l16 > qrow) s1 = -3e38f;
        if (k0 + 32 + l16 > qrow) s2 = -3e38f;
        if (k0 + 48 + l16 > qrow) s3 = -3e38f;
      }
      float mt = fmaxf(fmaxf(s0, s1), fmaxf(s2, s3));
#pragma unroll
      for (int off = 1; off < 16; off <<= 1)
        mt = fmaxf(mt, __shfl_xor(mt, off, 64));
      float mnew = fmaxf(mrun[r], mt);
      float alpha = exp2f(mrun[r] - mnew);
      mrun[r] = mnew;
      float p0 = exp2f(s0 - mnew), p1 = exp2f(s1 - mnew);
      float p2 = exp2f(s2 - mnew), p3 = exp2f(s3 - mnew);
      float rs = (p0 + p1) + (p2 + p3);
#pragma unroll
      for (int off = 1; off < 16; off <<= 1)
        rs += __shfl_xor(rs, off, 64);
      lrun[r] = lrun[r] * alpha + rs;
#pragma unroll
      for (int dn = 0; dn < 4; ++dn) accO[dn][r] *= alpha;
      int prow = (w * 16 + quad * 4 + r) * 72;
      Pl[prow + 0  + l16] = f2bf(p0);
      Pl[prow + 16 + l16] = f2bf(p1);
      Pl[prow + 32 + l16] = f2bf(p2);
      Pl[prow + 48 + l16] = f2bf(p3);
    }

    // O += P V  (per-wave Pl, no barrier needed)
#pragma unroll
    for (int kc = 0; kc < 2; ++kc) {
      bf16x8 pf = lds_load8(&Pl[(w * 16 + l16) * 72 + kc * 32 + quad * 8]);
#pragma unroll
      for (int dn = 0; dn < 4; ++dn) {
        bf16x8 vf = lds_load8(
            &Vt[(dn * 16 + l16) * 64 + (((kc * 4 + quad) ^ (l16 & 7)) * 8)]);
        accO[dn] = __builtin_amdgcn_mfma_f32_16x16x32_bf16(pf, vf, accO[dn], 0, 0, 0);
      }
    }
  }

#pragma unroll
  for (int r = 0; r < 4; ++r) {
    int q = qw + quad * 4 + r;
    float inv = 1.0f / lrun[r];
    size_t base = ((size_t)b * TT + q) * CC + h * DD;
#pragma unroll
    for (int dn = 0; dn < 4; ++dn)
      Yb[base + dn * 16 + l16] = f2bf(accO[dn][r] * inv);
  }
}

// ---------------- out = y @ W_proj + b_proj (fp32 out) ----------------
__global__ __launch_bounds__(256) void proj_gemm(
    const unsigned short* __restrict__ Yb, const unsigned short* __restrict__ Wt,
    const float* __restrict__ bp, float* __restrict__ out)
{
  __shared__ unsigned short Al[128 * 32];
  __shared__ unsigned short Bl[128 * 32];
  const int tid = threadIdx.x;
  const int w = tid >> 6, lane = tid & 63;
  const int l16 = lane & 15, quad = lane >> 4;
  const int nblk = blockIdx.x & 7, mblk = blockIdx.x >> 3;
  const int m0 = mblk * 128, n0 = nblk * 128;
  const int wm = (w & 1) * 64, wn = (w >> 1) * 64;

  const unsigned short* ga = Yb + (size_t)(m0 + w * 16 + (lane >> 2)) * 1024 + (lane & 3) * 8;
  const unsigned short* gb = Wt + (size_t)(n0 + w * 16 + (lane >> 2)) * 1024 + (lane & 3) * 8;
  unsigned short* la = &Al[w * 512];
  unsigned short* lb = &Bl[w * 512];

  f32x4 acc[4][4] = {};

  for (int kb = 0; kb < 1024; kb += 32) {
    __syncthreads();
    g2l16(ga + kb, la);
    g2l16(ga + kb + 65536, la + 2048);
    g2l16(gb + kb, lb);
    g2l16(gb + kb + 65536, lb + 2048);
    __syncthreads();
    bf16x8 af[4], bfr[4];
#pragma unroll
    for (int mi = 0; mi < 4; ++mi)
      af[mi] = lds_load8(&Al[(wm + mi * 16 + l16) * 32 + quad * 8]);
#pragma unroll
    for (int ni = 0; ni < 4; ++ni)
      bfr[ni] = lds_load8(&Bl[(wn + ni * 16 + l16) * 32 + quad * 8]);
#pragma unroll
    for (int mi = 0; mi < 4; ++mi)
#pragma unroll
      for (int ni = 0; ni < 4; ++ni)
        acc[mi][ni] = __builtin_amdgcn_mfma_f32_16x16x32_bf16(
            af[mi], bfr[ni], acc[mi][ni], 0, 0, 0);
  }

#pragma unroll
  for (int mi = 0; mi < 4; ++mi)
#pragma unroll
    for (int r = 0; r < 4; ++r) {
      int m = m0 + wm + mi * 16 + quad * 4 + r;
#pragma unroll
      for (int ni = 0; ni < 4; ++ni) {
        int c = n0 + wn + ni * 16 + l16;
        out[(size_t)m * 1024 + c] = acc[mi][ni][r] + bp[c];
      }
    }
}

extern "C" void kernel_launch(void* const* d_in, const int* in_sizes, int n_in,
                              void* d_out, int out_size, void* d_ws, size_t ws_size,
                              hipStream_t stream) {
  const float* x      = (const float*)d_in[0];
  const float* W_attn = (const float*)d_in[1];
  const float* b_attn = (const float*)d_in[2];
  const float* W_proj = (const float*)d_in[3];
  const float* b_proj = (const float*)d_in[4];
  const float* bQ     = (const float*)d_in[5];
  const float* bK     = (const float*)d_in[6];
  const float* bV     = (const float*)d_in[7];
  float* out = (float*)d_out;

  // workspace layout (u16 units); Yb aliases xb (xb dead after qkv_gemm).
  // total = 75.5 MB
  unsigned short* xb   = (unsigned short*)d_ws;        // 8,388,608
  unsigned short* Yb   = xb;                           // alias
  unsigned short* Wt_a = xb + 8388608;                 // 3,145,728
  unsigned short* Wt_p = Wt_a + 3145728;               // 1,048,576
  unsigned short* Qb   = Wt_p + 1048576;               // 8,388,608
  unsigned short* Kb   = Qb + 8388608;
  unsigned short* Vb   = Kb + 8388608;

  xcast<<<dim3(4096), dim3(256), 0, stream>>>(x, xb);
  wtrans<<<dim3(48, 16), dim3(256), 0, stream>>>(W_attn, Wt_a, 3072);
  wtrans<<<dim3(16, 16), dim3(256), 0, stream>>>(W_proj, Wt_p, 1024);
  qkv_gemm<<<dim3(64 * 24), dim3(256), 0, stream>>>(xb, Wt_a, b_attn, bQ, bK, bV,
                                                    Qb, Kb, Vb);
  attn_kernel<<<dim3(32 * 64), dim3(256), 0, stream>>>(Qb, Kb, Vb, Yb);
  proj_gemm<<<dim3(64 * 8), dim3(256), 0, stream>>>(Yb, Wt_p, b_proj, out);
}

// Round 4
// 299.441 us; speedup vs baseline: 2.6855x; 1.1037x over previous
//
#include <hip/hip_runtime.h>
#include <hip/hip_bf16.h>

#define BB 4
#define TT 2048
#define CC 1024
#define HH 16
#define DD 64

typedef __bf16 bf16x8 __attribute__((ext_vector_type(8)));
typedef float f32x4 __attribute__((ext_vector_type(4)));
typedef unsigned int u32x4 __attribute__((ext_vector_type(4)));
typedef unsigned short u16x8 __attribute__((ext_vector_type(8)));
typedef unsigned short u16x4 __attribute__((ext_vector_type(4)));
typedef unsigned int u32;

__device__ __forceinline__ unsigned short f2bf(float f) {
  u32 u = __builtin_bit_cast(u32, f);
  u += 0x7fff + ((u >> 16) & 1);   // RNE
  return (unsigned short)(u >> 16);
}

__device__ __forceinline__ bf16x8 lds_load8(const unsigned short* p) {
  u32x4 t = *(const u32x4*)p;
  return __builtin_bit_cast(bf16x8, t);
}

// async 16B global->LDS (dest = wave-uniform base + lane*16)
__device__ __forceinline__ void g2l16(const unsigned short* g, unsigned short* l) {
  __builtin_amdgcn_global_load_lds(
      (const __attribute__((address_space(1))) u32*)g,
      (__attribute__((address_space(3))) u32*)l, 16, 0, 0);
}

// ---------------- prep: x fp32 -> bf16 ----------------
__global__ __launch_bounds__(256) void xcast(const float* __restrict__ x,
                                             unsigned short* __restrict__ xb) {
  int i = (blockIdx.x * 256 + threadIdx.x) * 8;
  f32x4 a = *(const f32x4*)(x + i);
  f32x4 b = *(const f32x4*)(x + i + 4);
  u16x8 o;
  o[0] = f2bf(a[0]); o[1] = f2bf(a[1]); o[2] = f2bf(a[2]); o[3] = f2bf(a[3]);
  o[4] = f2bf(b[0]); o[5] = f2bf(b[1]); o[6] = f2bf(b[2]); o[7] = f2bf(b[3]);
  *(u16x8*)(xb + i) = o;
}

// ---------------- prep: W [K=1024][N] fp32 -> Wt [N][1024] bf16 ----------------
__global__ __launch_bounds__(256) void wtrans(const float* __restrict__ W,
                                              unsigned short* __restrict__ Wt, int N) {
  __shared__ unsigned short T[64 * 68];
  const int tid = threadIdx.x;
  const int n0 = blockIdx.x * 64, k0 = blockIdx.y * 64;
#pragma unroll
  for (int it = 0; it < 4; ++it) {
    int idx = it * 256 + tid;
    int kk = idx >> 4, nn = (idx & 15) * 4;
    f32x4 v = *(const f32x4*)(W + (size_t)(k0 + kk) * N + n0 + nn);
    u16x4 p;
    p[0] = f2bf(v[0]); p[1] = f2bf(v[1]); p[2] = f2bf(v[2]); p[3] = f2bf(v[3]);
    *(u16x4*)(&T[kk * 68 + nn]) = p;
  }
  __syncthreads();
#pragma unroll
  for (int it = 0; it < 4; ++it) {
    int idx = it * 256 + tid;
    int nn = idx >> 4, kc = (idx & 15) * 4;
    u16x4 o;
    o[0] = T[(kc + 0) * 68 + nn];
    o[1] = T[(kc + 1) * 68 + nn];
    o[2] = T[(kc + 2) * 68 + nn];
    o[3] = T[(kc + 3) * 68 + nn];
    *(u16x4*)(Wt + (size_t)(n0 + nn) * 1024 + k0 + kc) = o;
  }
}

// ---------------- qkv = x @ W_attn + biases ----------------
// Q pre-scaled by 0.125*log2(e). Q,K stored [B,H,T,D]; V stored TRANSPOSED [B,H,D,T].
__global__ __launch_bounds__(256) void qkv_gemm(
    const unsigned short* __restrict__ xb, const unsigned short* __restrict__ Wt,
    const float* __restrict__ b_attn, const float* __restrict__ bQ,
    const float* __restrict__ bK, const float* __restrict__ bV,
    unsigned short* __restrict__ Qb, unsigned short* __restrict__ Kb,
    unsigned short* __restrict__ Vb)
{
  __shared__ unsigned short Al[128 * 32];
  __shared__ unsigned short Bl[128 * 32];
  const int tid = threadIdx.x;
  const int w = tid >> 6, lane = tid & 63;
  const int l16 = lane & 15, quad = lane >> 4;
  const int nblk = blockIdx.x % 24, mblk = blockIdx.x / 24;
  const int m0 = mblk * 128, n0 = nblk * 128;
  const int wm = (w & 1) * 64, wn = (w >> 1) * 64;

  const unsigned short* ga = xb + (size_t)(m0 + w * 16 + (lane >> 2)) * 1024 + (lane & 3) * 8;
  const unsigned short* gb = Wt + (size_t)(n0 + w * 16 + (lane >> 2)) * 1024 + (lane & 3) * 8;
  unsigned short* la = &Al[w * 512];
  unsigned short* lb = &Bl[w * 512];

  f32x4 acc[4][4] = {};

  for (int kb = 0; kb < 1024; kb += 32) {
    __syncthreads();
    g2l16(ga + kb, la);
    g2l16(ga + kb + 65536, la + 2048);
    g2l16(gb + kb, lb);
    g2l16(gb + kb + 65536, lb + 2048);
    __syncthreads();
    bf16x8 af[4], bfr[4];
#pragma unroll
    for (int mi = 0; mi < 4; ++mi)
      af[mi] = lds_load8(&Al[(wm + mi * 16 + l16) * 32 + quad * 8]);
#pragma unroll
    for (int ni = 0; ni < 4; ++ni)
      bfr[ni] = lds_load8(&Bl[(wn + ni * 16 + l16) * 32 + quad * 8]);
#pragma unroll
    for (int mi = 0; mi < 4; ++mi)
#pragma unroll
      for (int ni = 0; ni < 4; ++ni)
        acc[mi][ni] = __builtin_amdgcn_mfma_f32_16x16x32_bf16(
            af[mi], bfr[ni], acc[mi][ni], 0, 0, 0);
  }

  unsigned short* dst[4];
  float biasv[4], sc[4];
  int st[4];
#pragma unroll
  for (int ni = 0; ni < 4; ++ni) {
    int col = n0 + wn + ni * 16 + l16;
    int sec = col >> 10, cc = col & 1023;
    const float* hb = (sec == 0) ? bQ : (sec == 1 ? bK : bV);
    biasv[ni] = b_attn[col] + hb[cc];
    sc[ni] = (sec == 0) ? 0.125f * 1.44269504f : 1.0f;
    if (sec == 2) {   // V transposed: [h][d][t]
      dst[ni] = Vb + (size_t)(cc >> 6) * (DD * TT) + (size_t)(cc & 63) * TT;
      st[ni] = 1;
    } else {
      unsigned short* base = (sec == 0) ? Qb : Kb;
      dst[ni] = base + (size_t)(cc >> 6) * (TT * DD) + (cc & 63);
      st[ni] = 64;
    }
  }
#pragma unroll
  for (int mi = 0; mi < 4; ++mi)
#pragma unroll
    for (int r = 0; r < 4; ++r) {
      int m = m0 + wm + mi * 16 + quad * 4 + r;
      int bidx = m >> 11, t = m & 2047;
      size_t co = (size_t)bidx * (HH * TT * DD);
#pragma unroll
      for (int ni = 0; ni < 4; ++ni)
        dst[ni][co + (size_t)t * st[ni]] = f2bf((acc[mi][ni][r] + biasv[ni]) * sc[ni]);
    }
}

// ---------------- causal flash attention, static-max softmax ----------------
// block = 4 waves x 32 q-rows = 128 rows; BK=64; grid = 16 qt x 64 bh (LPT order).
// Keys permuted within tile: Kl row 16b+a holds key 4a+b  ->  lane's 4 P values
// are contiguous (one ds_write_b64). Row-sum via MFMA against all-ones B-frag.
__global__ __launch_bounds__(256) void attn_kernel(
    const unsigned short* __restrict__ Qb, const unsigned short* __restrict__ Kb,
    const unsigned short* __restrict__ Vtg, unsigned short* __restrict__ Yb)
{
  __shared__ unsigned short Kl[64 * 64];
  __shared__ unsigned short Vl[64 * 64];
  __shared__ unsigned short Pl[4 * 32 * 72];
  const int tid = threadIdx.x;
  const int w = tid >> 6, lane = tid & 63;
  const int l16 = lane & 15, quad = lane >> 4;
  const int qt = 15 - (blockIdx.x >> 6);   // longest first (LPT)
  const int bh = blockIdx.x & 63;          // bh%8 fixed per XCD -> K/V L2 locality
  const int b = bh >> 4, h = bh & 15;
  const int q0 = qt * 128, qw = q0 + w * 32;

  const unsigned short* Qg = Qb + (size_t)bh * TT * DD;
  const unsigned short* Kg = Kb + (size_t)bh * TT * DD;
  const unsigned short* Vg = Vtg + (size_t)bh * DD * TT;   // [d][t]

  // Q fragments (pre-scaled by 0.125*log2e)
  bf16x8 qf[2][2];
#pragma unroll
  for (int mi = 0; mi < 2; ++mi)
#pragma unroll
    for (int dk = 0; dk < 2; ++dk) {
      u32x4 t = *(const u32x4*)(Qg + (size_t)(qw + mi * 16 + l16) * 64 + dk * 32 + quad * 8);
      qf[mi][dk] = __builtin_bit_cast(bf16x8, t);
    }

  f32x4 accO[2][4] = {};
  f32x4 accL[2] = {};
  u16x8 o16;
#pragma unroll
  for (int j = 0; j < 8; ++j) o16[j] = 0x3F80;   // bf16 1.0
  const bf16x8 onesf = __builtin_bit_cast(bf16x8, o16);

  // staging: LDS row = w*8 + lane/8 (and +32), phys chunk = lane%8
  const int srow = w * 8 + (lane >> 3);
  const int schunk = ((lane & 7) ^ (srow & 7)) * 8;       // XOR bank swizzle
  const int kkey = 4 * (srow & 15) + (srow >> 4);          // key permutation
  const unsigned short* gk1 = Kg + (size_t)kkey * 64 + schunk;
  const unsigned short* gk2 = Kg + (size_t)(kkey + 2) * 64 + schunk;
  const unsigned short* gv1 = Vg + (size_t)srow * TT + schunk;
  const unsigned short* gv2 = Vg + (size_t)(srow + 32) * TT + schunk;
  unsigned short* klw = &Kl[w * 512];
  unsigned short* vlw = &Vl[w * 512];

  const int kend = q0 + 64;   // waves 2,3 need one tile past q0
  for (int k0 = 0; k0 <= kend; k0 += 64) {
    __syncthreads();
    g2l16(gk1 + (size_t)k0 * 64, klw);
    g2l16(gk2 + (size_t)k0 * 64, klw + 2048);
    g2l16(gv1 + k0, vlw);
    g2l16(gv2 + k0, vlw + 2048);
    __syncthreads();
    if (k0 > qw + 31) continue;   // wave-uniform; staging+barriers stay matched

    // S = Q K^T
    f32x4 accS[2][4] = {};
#pragma unroll
    for (int ni = 0; ni < 4; ++ni)
#pragma unroll
      for (int dk = 0; dk < 2; ++dk) {
        bf16x8 kf = lds_load8(
            &Kl[(ni * 16 + l16) * 64 + (((dk * 4 + quad) ^ (l16 & 7)) * 8)]);
#pragma unroll
        for (int mi = 0; mi < 2; ++mi)
          accS[mi][ni] = __builtin_amdgcn_mfma_f32_16x16x32_bf16(
              qf[mi][dk], kf, accS[mi][ni], 0, 0, 0);
      }

    // static-max softmax: p = exp2(s); accS[ni] col l16 <-> key k0 + 4*l16 + ni
    // Mask needed iff tile contains any key beyond the wave's SMALLEST row (qw).
    const bool maskT = (k0 + 63 > qw);
#pragma unroll
    for (int mi = 0; mi < 2; ++mi)
#pragma unroll
      for (int r = 0; r < 4; ++r) {
        int qrow = qw + mi * 16 + quad * 4 + r;
        float s0 = accS[mi][0][r], s1 = accS[mi][1][r];
        float s2 = accS[mi][2][r], s3 = accS[mi][3][r];
        if (maskT) {
          int kb = k0 + 4 * l16;
          if (kb + 0 > qrow) s0 = -3e38f;
          if (kb + 1 > qrow) s1 = -3e38f;
          if (kb + 2 > qrow) s2 = -3e38f;
          if (kb + 3 > qrow) s3 = -3e38f;
        }
        u16x4 pk;
        pk[0] = f2bf(exp2f(s0));
        pk[1] = f2bf(exp2f(s1));
        pk[2] = f2bf(exp2f(s2));
        pk[3] = f2bf(exp2f(s3));
        *(u16x4*)(&Pl[(w * 32 + mi * 16 + quad * 4 + r) * 72 + 4 * l16]) = pk;
      }

    // O += P V ; L += P . ones   (Pl per-wave, no barrier)
#pragma unroll
    for (int kc = 0; kc < 2; ++kc) {
      bf16x8 pf[2];
#pragma unroll
      for (int mi = 0; mi < 2; ++mi)
        pf[mi] = lds_load8(&Pl[(w * 32 + mi * 16 + l16) * 72 + kc * 32 + quad * 8]);
#pragma unroll
      for (int dn = 0; dn < 4; ++dn) {
        bf16x8 vf = lds_load8(
            &Vl[(dn * 16 + l16) * 64 + (((kc * 4 + quad) ^ (l16 & 7)) * 8)]);
#pragma unroll
        for (int mi = 0; mi < 2; ++mi)
          accO[mi][dn] = __builtin_amdgcn_mfma_f32_16x16x32_bf16(
              pf[mi], vf, accO[mi][dn], 0, 0, 0);
      }
#pragma unroll
      for (int mi = 0; mi < 2; ++mi)
        accL[mi] = __builtin_amdgcn_mfma_f32_16x16x32_bf16(
            pf[mi], onesf, accL[mi], 0, 0, 0);
    }
  }

#pragma unroll
  for (int mi = 0; mi < 2; ++mi)
#pragma unroll
    for (int r = 0; r < 4; ++r) {
      int q = qw + mi * 16 + quad * 4 + r;
      float inv = 1.0f / accL[mi][r];
      size_t base = ((size_t)b * TT + q) * CC + h * DD;
#pragma unroll
      for (int dn = 0; dn < 4; ++dn)
        Yb[base + dn * 16 + l16] = f2bf(accO[mi][dn][r] * inv);
    }
}

// ---------------- out = y @ W_proj + b_proj (fp32 out) ----------------
__global__ __launch_bounds__(256) void proj_gemm(
    const unsigned short* __restrict__ Yb, const unsigned short* __restrict__ Wt,
    const float* __restrict__ bp, float* __restrict__ out)
{
  __shared__ unsigned short Al[128 * 32];
  __shared__ unsigned short Bl[128 * 32];
  const int tid = threadIdx.x;
  const int w = tid >> 6, lane = tid & 63;
  const int l16 = lane & 15, quad = lane >> 4;
  const int nblk = blockIdx.x & 7, mblk = blockIdx.x >> 3;
  const int m0 = mblk * 128, n0 = nblk * 128;
  const int wm = (w & 1) * 64, wn = (w >> 1) * 64;

  const unsigned short* ga = Yb + (size_t)(m0 + w * 16 + (lane >> 2)) * 1024 + (lane & 3) * 8;
  const unsigned short* gb = Wt + (size_t)(n0 + w * 16 + (lane >> 2)) * 1024 + (lane & 3) * 8;
  unsigned short* la = &Al[w * 512];
  unsigned short* lb = &Bl[w * 512];

  f32x4 acc[4][4] = {};

  for (int kb = 0; kb < 1024; kb += 32) {
    __syncthreads();
    g2l16(ga + kb, la);
    g2l16(ga + kb + 65536, la + 2048);
    g2l16(gb + kb, lb);
    g2l16(gb + kb + 65536, lb + 2048);
    __syncthreads();
    bf16x8 af[4], bfr[4];
#pragma unroll
    for (int mi = 0; mi < 4; ++mi)
      af[mi] = lds_load8(&Al[(wm + mi * 16 + l16) * 32 + quad * 8]);
#pragma unroll
    for (int ni = 0; ni < 4; ++ni)
      bfr[ni] = lds_load8(&Bl[(wn + ni * 16 + l16) * 32 + quad * 8]);
#pragma unroll
    for (int mi = 0; mi < 4; ++mi)
#pragma unroll
      for (int ni = 0; ni < 4; ++ni)
        acc[mi][ni] = __builtin_amdgcn_mfma_f32_16x16x32_bf16(
            af[mi], bfr[ni], acc[mi][ni], 0, 0, 0);
  }

#pragma unroll
  for (int mi = 0; mi < 4; ++mi)
#pragma unroll
    for (int r = 0; r < 4; ++r) {
      int m = m0 + wm + mi * 16 + quad * 4 + r;
#pragma unroll
      for (int ni = 0; ni < 4; ++ni) {
        int c = n0 + wn + ni * 16 + l16;
        out[(size_t)m * 1024 + c] = acc[mi][ni][r] + bp[c];
      }
    }
}

extern "C" void kernel_launch(void* const* d_in, const int* in_sizes, int n_in,
                              void* d_out, int out_size, void* d_ws, size_t ws_size,
                              hipStream_t stream) {
  const float* x      = (const float*)d_in[0];
  const float* W_attn = (const float*)d_in[1];
  const float* b_attn = (const float*)d_in[2];
  const float* W_proj = (const float*)d_in[3];
  const float* b_proj = (const float*)d_in[4];
  const float* bQ     = (const float*)d_in[5];
  const float* bK     = (const float*)d_in[6];
  const float* bV     = (const float*)d_in[7];
  float* out = (float*)d_out;

  unsigned short* xb   = (unsigned short*)d_ws;        // 8,388,608
  unsigned short* Yb   = xb;                           // alias (xb dead after qkv)
  unsigned short* Wt_a = xb + 8388608;                 // 3,145,728
  unsigned short* Wt_p = Wt_a + 3145728;               // 1,048,576
  unsigned short* Qb   = Wt_p + 1048576;               // 8,388,608
  unsigned short* Kb   = Qb + 8388608;
  unsigned short* Vb   = Kb + 8388608;                 // [B,H,D,T]

  xcast<<<dim3(4096), dim3(256), 0, stream>>>(x, xb);
  wtrans<<<dim3(48, 16), dim3(256), 0, stream>>>(W_attn, Wt_a, 3072);
  wtrans<<<dim3(16, 16), dim3(256), 0, stream>>>(W_proj, Wt_p, 1024);
  qkv_gemm<<<dim3(64 * 24), dim3(256), 0, stream>>>(xb, Wt_a, b_attn, bQ, bK, bV,
                                                    Qb, Kb, Vb);
  attn_kernel<<<dim3(16 * 64), dim3(256), 0, stream>>>(Qb, Kb, Vb, Yb);
  proj_gemm<<<dim3(64 * 8), dim3(256), 0, stream>>>(Yb, Wt_p, b_proj, out);
}

// Round 5
// 280.141 us; speedup vs baseline: 2.8705x; 1.0689x over previous
//
#include <hip/hip_runtime.h>
#include <hip/hip_bf16.h>

#define BB 4
#define TT 2048
#define CC 1024
#define HH 16
#define DD 64

typedef __bf16 bf16x8 __attribute__((ext_vector_type(8)));
typedef float f32x4 __attribute__((ext_vector_type(4)));
typedef unsigned int u32x4 __attribute__((ext_vector_type(4)));
typedef unsigned int u32x2 __attribute__((ext_vector_type(2)));
typedef unsigned short u16x8 __attribute__((ext_vector_type(8)));
typedef unsigned short u16x4 __attribute__((ext_vector_type(4)));
typedef unsigned int u32;

__device__ __forceinline__ unsigned short f2bf(float f) {
  u32 u = __builtin_bit_cast(u32, f);
  u += 0x7fff + ((u >> 16) & 1);   // RNE
  return (unsigned short)(u >> 16);
}

__device__ __forceinline__ bf16x8 lds_load8(const unsigned short* p) {
  u32x4 t = *(const u32x4*)p;
  return __builtin_bit_cast(bf16x8, t);
}

// async 16B global->LDS (dest = wave-uniform base + lane*16)
__device__ __forceinline__ void g2l16(const unsigned short* g, unsigned short* l) {
  __builtin_amdgcn_global_load_lds(
      (const __attribute__((address_space(1))) u32*)g,
      (__attribute__((address_space(3))) u32*)l, 16, 0, 0);
}

// ---------------- fused prep: xcast + W_attn^T + W_proj^T ----------------
__global__ __launch_bounds__(256) void prep(
    const float* __restrict__ x, const float* __restrict__ Wa,
    const float* __restrict__ Wp, unsigned short* __restrict__ xb,
    unsigned short* __restrict__ Wta, unsigned short* __restrict__ Wtp)
{
  __shared__ unsigned short T[64 * 68];
  const int tid = threadIdx.x;
  const int bid = blockIdx.x;
  if (bid < 4096) {                       // x fp32 -> bf16
    int i = (bid * 256 + tid) * 8;
    f32x4 a = *(const f32x4*)(x + i);
    f32x4 b = *(const f32x4*)(x + i + 4);
    u16x8 o;
    o[0] = f2bf(a[0]); o[1] = f2bf(a[1]); o[2] = f2bf(a[2]); o[3] = f2bf(a[3]);
    o[4] = f2bf(b[0]); o[5] = f2bf(b[1]); o[6] = f2bf(b[2]); o[7] = f2bf(b[3]);
    *(u16x8*)(xb + i) = o;
    return;
  }
  const float* W; unsigned short* Wt; int N, n0, k0;
  if (bid < 4096 + 768) {
    int b2 = bid - 4096;  W = Wa; Wt = Wta; N = 3072;
    n0 = (b2 % 48) * 64;  k0 = (b2 / 48) * 64;
  } else {
    int b2 = bid - 4864;  W = Wp; Wt = Wtp; N = 1024;
    n0 = (b2 % 16) * 64;  k0 = (b2 / 16) * 64;
  }
#pragma unroll
  for (int it = 0; it < 4; ++it) {
    int idx = it * 256 + tid;
    int kk = idx >> 4, nn = (idx & 15) * 4;
    f32x4 v = *(const f32x4*)(W + (size_t)(k0 + kk) * N + n0 + nn);
    u16x4 p;
    p[0] = f2bf(v[0]); p[1] = f2bf(v[1]); p[2] = f2bf(v[2]); p[3] = f2bf(v[3]);
    *(u16x4*)(&T[kk * 68 + nn]) = p;
  }
  __syncthreads();
#pragma unroll
  for (int it = 0; it < 4; ++it) {
    int idx = it * 256 + tid;
    int nn = idx >> 4, kc = (idx & 15) * 4;
    u16x4 o;
    o[0] = T[(kc + 0) * 68 + nn];
    o[1] = T[(kc + 1) * 68 + nn];
    o[2] = T[(kc + 2) * 68 + nn];
    o[3] = T[(kc + 3) * 68 + nn];
    *(u16x4*)(Wt + (size_t)(n0 + nn) * 1024 + k0 + kc) = o;
  }
}

// ---------------- qkv = x @ W_attn + biases, BK=64 ----------------
// Q pre-scaled by 0.125*log2(e). Q,K stored [B,H,T,D]; V stored TRANSPOSED [B,H,D,T].
// 64-wide LDS rows with XOR chunk swizzle: phys_chunk = logical_chunk ^ (row&7).
__global__ __launch_bounds__(256) void qkv_gemm(
    const unsigned short* __restrict__ xb, const unsigned short* __restrict__ Wt,
    const float* __restrict__ b_attn, const float* __restrict__ bQ,
    const float* __restrict__ bK, const float* __restrict__ bV,
    unsigned short* __restrict__ Qb, unsigned short* __restrict__ Kb,
    unsigned short* __restrict__ Vb)
{
  __shared__ unsigned short Al[128 * 64];
  __shared__ unsigned short Bl[128 * 64];
  const int tid = threadIdx.x;
  const int w = tid >> 6, lane = tid & 63;
  const int l16 = lane & 15, quad = lane >> 4;
  const int nblk = blockIdx.x % 24, mblk = blockIdx.x / 24;
  const int m0 = mblk * 128, n0 = nblk * 128;
  const int wm = (w & 1) * 64, wn = (w >> 1) * 64;

  const int srow = lane >> 3;                           // 0..7
  const int schunk = ((lane & 7) ^ (srow & 7)) * 8;     // XOR bank swizzle
  const unsigned short* ga = xb + (size_t)(m0 + w * 8 + srow) * 1024 + schunk;
  const unsigned short* gb = Wt + (size_t)(n0 + w * 8 + srow) * 1024 + schunk;
  unsigned short* la = &Al[(w * 8) * 64];
  unsigned short* lb = &Bl[(w * 8) * 64];

  f32x4 acc[4][4] = {};

  for (int kb = 0; kb < 1024; kb += 64) {
    __syncthreads();
#pragma unroll
    for (int i = 0; i < 4; ++i) {
      g2l16(ga + kb + (size_t)i * 32 * 1024, la + i * 32 * 64);
      g2l16(gb + kb + (size_t)i * 32 * 1024, lb + i * 32 * 64);
    }
    __syncthreads();
    bf16x8 af[4][2], bfr[4][2];
#pragma unroll
    for (int mi = 0; mi < 4; ++mi)
#pragma unroll
      for (int dk = 0; dk < 2; ++dk)
        af[mi][dk] = lds_load8(
            &Al[(wm + mi * 16 + l16) * 64 + (((dk * 4 + quad) ^ (l16 & 7)) * 8)]);
#pragma unroll
    for (int ni = 0; ni < 4; ++ni)
#pragma unroll
      for (int dk = 0; dk < 2; ++dk)
        bfr[ni][dk] = lds_load8(
            &Bl[(wn + ni * 16 + l16) * 64 + (((dk * 4 + quad) ^ (l16 & 7)) * 8)]);
#pragma unroll
    for (int mi = 0; mi < 4; ++mi)
#pragma unroll
      for (int ni = 0; ni < 4; ++ni) {
        acc[mi][ni] = __builtin_amdgcn_mfma_f32_16x16x32_bf16(
            af[mi][0], bfr[ni][0], acc[mi][ni], 0, 0, 0);
        acc[mi][ni] = __builtin_amdgcn_mfma_f32_16x16x32_bf16(
            af[mi][1], bfr[ni][1], acc[mi][ni], 0, 0, 0);
      }
  }

  unsigned short* dst[4];
  float biasv[4], sc[4];
  int st[4];
#pragma unroll
  for (int ni = 0; ni < 4; ++ni) {
    int col = n0 + wn + ni * 16 + l16;
    int sec = col >> 10, cc = col & 1023;
    const float* hb = (sec == 0) ? bQ : (sec == 1 ? bK : bV);
    biasv[ni] = b_attn[col] + hb[cc];
    sc[ni] = (sec == 0) ? 0.125f * 1.44269504f : 1.0f;
    if (sec == 2) {   // V transposed: [h][d][t]
      dst[ni] = Vb + (size_t)(cc >> 6) * (DD * TT) + (size_t)(cc & 63) * TT;
      st[ni] = 1;
    } else {
      unsigned short* base = (sec == 0) ? Qb : Kb;
      dst[ni] = base + (size_t)(cc >> 6) * (TT * DD) + (cc & 63);
      st[ni] = 64;
    }
  }
#pragma unroll
  for (int mi = 0; mi < 4; ++mi)
#pragma unroll
    for (int r = 0; r < 4; ++r) {
      int m = m0 + wm + mi * 16 + quad * 4 + r;
      int bidx = m >> 11, t = m & 2047;
      size_t co = (size_t)bidx * (HH * TT * DD);
#pragma unroll
      for (int ni = 0; ni < 4; ++ni)
        dst[ni][co + (size_t)t * st[ni]] = f2bf((acc[mi][ni][r] + biasv[ni]) * sc[ni]);
    }
}

// ---------------- causal flash attention, static-max softmax ----------------
// block = 4 waves x 32 q-rows = 128 rows; BK=64; grid = 16 qt x 64 bh (LPT order).
// Keys permuted within tile (Kl row 16b+a holds key 4a+b); P-pack via v_perm_b32
// truncation (2 VALU for 4 values); row-sum via MFMA against all-ones B-frag.
__global__ __launch_bounds__(256) void attn_kernel(
    const unsigned short* __restrict__ Qb, const unsigned short* __restrict__ Kb,
    const unsigned short* __restrict__ Vtg, unsigned short* __restrict__ Yb)
{
  __shared__ unsigned short Kl[64 * 64];
  __shared__ unsigned short Vl[64 * 64];
  __shared__ unsigned short Pl[4 * 32 * 72];
  const int tid = threadIdx.x;
  const int w = tid >> 6, lane = tid & 63;
  const int l16 = lane & 15, quad = lane >> 4;
  const int qt = 15 - (blockIdx.x >> 6);   // longest first (LPT)
  const int bh = blockIdx.x & 63;          // bh%8 fixed per XCD -> K/V L2 locality
  const int b = bh >> 4, h = bh & 15;
  const int q0 = qt * 128, qw = q0 + w * 32;

  const unsigned short* Qg = Qb + (size_t)bh * TT * DD;
  const unsigned short* Kg = Kb + (size_t)bh * TT * DD;
  const unsigned short* Vg = Vtg + (size_t)bh * DD * TT;   // [d][t]

  // Q fragments (pre-scaled by 0.125*log2e)
  bf16x8 qf[2][2];
#pragma unroll
  for (int mi = 0; mi < 2; ++mi)
#pragma unroll
    for (int dk = 0; dk < 2; ++dk) {
      u32x4 t = *(const u32x4*)(Qg + (size_t)(qw + mi * 16 + l16) * 64 + dk * 32 + quad * 8);
      qf[mi][dk] = __builtin_bit_cast(bf16x8, t);
    }

  f32x4 accO[2][4] = {};
  f32x4 accL[2] = {};
  u16x8 o16;
#pragma unroll
  for (int j = 0; j < 8; ++j) o16[j] = 0x3F80;   // bf16 1.0
  const bf16x8 onesf = __builtin_bit_cast(bf16x8, o16);

  // staging: LDS row = w*8 + lane/8 (and +32), phys chunk = lane%8
  const int srow = w * 8 + (lane >> 3);
  const int schunk = ((lane & 7) ^ (srow & 7)) * 8;       // XOR bank swizzle
  const int kkey = 4 * (srow & 15) + (srow >> 4);          // key permutation
  const unsigned short* gk1 = Kg + (size_t)kkey * 64 + schunk;
  const unsigned short* gk2 = Kg + (size_t)(kkey + 2) * 64 + schunk;
  const unsigned short* gv1 = Vg + (size_t)srow * TT + schunk;
  const unsigned short* gv2 = Vg + (size_t)(srow + 32) * TT + schunk;
  unsigned short* klw = &Kl[w * 512];
  unsigned short* vlw = &Vl[w * 512];

  const int kend = q0 + 64;   // waves 2,3 need one tile past q0
  for (int k0 = 0; k0 <= kend; k0 += 64) {
    __syncthreads();
    g2l16(gk1 + (size_t)k0 * 64, klw);
    g2l16(gk2 + (size_t)k0 * 64, klw + 2048);
    g2l16(gv1 + k0, vlw);
    g2l16(gv2 + k0, vlw + 2048);
    __syncthreads();
    if (k0 > qw + 31) continue;   // wave-uniform; staging+barriers stay matched

    // S = Q K^T
    f32x4 accS[2][4] = {};
#pragma unroll
    for (int ni = 0; ni < 4; ++ni)
#pragma unroll
      for (int dk = 0; dk < 2; ++dk) {
        bf16x8 kf = lds_load8(
            &Kl[(ni * 16 + l16) * 64 + (((dk * 4 + quad) ^ (l16 & 7)) * 8)]);
#pragma unroll
        for (int mi = 0; mi < 2; ++mi)
          accS[mi][ni] = __builtin_amdgcn_mfma_f32_16x16x32_bf16(
              qf[mi][dk], kf, accS[mi][ni], 0, 0, 0);
      }

    // static-max softmax: p = exp2(s); accS[ni] col l16 <-> key k0 + 4*l16 + ni
    // Mask needed iff tile contains any key beyond the wave's SMALLEST row (qw).
    const bool maskT = (k0 + 63 > qw);
#pragma unroll
    for (int mi = 0; mi < 2; ++mi)
#pragma unroll
      for (int r = 0; r < 4; ++r) {
        int qrow = qw + mi * 16 + quad * 4 + r;
        float s0 = accS[mi][0][r], s1 = accS[mi][1][r];
        float s2 = accS[mi][2][r], s3 = accS[mi][3][r];
        if (maskT) {
          int kb = k0 + 4 * l16;
          if (kb + 0 > qrow) s0 = -3e38f;
          if (kb + 1 > qrow) s1 = -3e38f;
          if (kb + 2 > qrow) s2 = -3e38f;
          if (kb + 3 > qrow) s3 = -3e38f;
        }
        u32 e0 = __builtin_bit_cast(u32, exp2f(s0));
        u32 e1 = __builtin_bit_cast(u32, exp2f(s1));
        u32 e2 = __builtin_bit_cast(u32, exp2f(s2));
        u32 e3 = __builtin_bit_cast(u32, exp2f(s3));
        u32x2 pv;
        pv[0] = __builtin_amdgcn_perm(e1, e0, 0x07060302);  // [hi16(e0),hi16(e1)]
        pv[1] = __builtin_amdgcn_perm(e3, e2, 0x07060302);
        *(u32x2*)(&Pl[(w * 32 + mi * 16 + quad * 4 + r) * 72 + 4 * l16]) = pv;
      }

    // O += P V ; L += P . ones   (Pl per-wave, no barrier)
#pragma unroll
    for (int kc = 0; kc < 2; ++kc) {
      bf16x8 pf[2];
#pragma unroll
      for (int mi = 0; mi < 2; ++mi)
        pf[mi] = lds_load8(&Pl[(w * 32 + mi * 16 + l16) * 72 + kc * 32 + quad * 8]);
#pragma unroll
      for (int dn = 0; dn < 4; ++dn) {
        bf16x8 vf = lds_load8(
            &Vl[(dn * 16 + l16) * 64 + (((kc * 4 + quad) ^ (l16 & 7)) * 8)]);
#pragma unroll
        for (int mi = 0; mi < 2; ++mi)
          accO[mi][dn] = __builtin_amdgcn_mfma_f32_16x16x32_bf16(
              pf[mi], vf, accO[mi][dn], 0, 0, 0);
      }
#pragma unroll
      for (int mi = 0; mi < 2; ++mi)
        accL[mi] = __builtin_amdgcn_mfma_f32_16x16x32_bf16(
            pf[mi], onesf, accL[mi], 0, 0, 0);
    }
  }

#pragma unroll
  for (int mi = 0; mi < 2; ++mi)
#pragma unroll
    for (int r = 0; r < 4; ++r) {
      int q = qw + mi * 16 + quad * 4 + r;
      float inv = 1.0f / accL[mi][r];
      size_t base = ((size_t)b * TT + q) * CC + h * DD;
#pragma unroll
      for (int dn = 0; dn < 4; ++dn)
        Yb[base + dn * 16 + l16] = f2bf(accO[mi][dn][r] * inv);
    }
}

// ---------------- out = y @ W_proj + b_proj (fp32 out), BK=64 ----------------
__global__ __launch_bounds__(256) void proj_gemm(
    const unsigned short* __restrict__ Yb, const unsigned short* __restrict__ Wt,
    const float* __restrict__ bp, float* __restrict__ out)
{
  __shared__ unsigned short Al[128 * 64];
  __shared__ unsigned short Bl[128 * 64];
  const int tid = threadIdx.x;
  const int w = tid >> 6, lane = tid & 63;
  const int l16 = lane & 15, quad = lane >> 4;
  const int nblk = blockIdx.x & 7, mblk = blockIdx.x >> 3;
  const int m0 = mblk * 128, n0 = nblk * 128;
  const int wm = (w & 1) * 64, wn = (w >> 1) * 64;

  const int srow = lane >> 3;
  const int schunk = ((lane & 7) ^ (srow & 7)) * 8;
  const unsigned short* ga = Yb + (size_t)(m0 + w * 8 + srow) * 1024 + schunk;
  const unsigned short* gb = Wt + (size_t)(n0 + w * 8 + srow) * 1024 + schunk;
  unsigned short* la = &Al[(w * 8) * 64];
  unsigned short* lb = &Bl[(w * 8) * 64];

  f32x4 acc[4][4] = {};

  for (int kb = 0; kb < 1024; kb += 64) {
    __syncthreads();
#pragma unroll
    for (int i = 0; i < 4; ++i) {
      g2l16(ga + kb + (size_t)i * 32 * 1024, la + i * 32 * 64);
      g2l16(gb + kb + (size_t)i * 32 * 1024, lb + i * 32 * 64);
    }
    __syncthreads();
    bf16x8 af[4][2], bfr[4][2];
#pragma unroll
    for (int mi = 0; mi < 4; ++mi)
#pragma unroll
      for (int dk = 0; dk < 2; ++dk)
        af[mi][dk] = lds_load8(
            &Al[(wm + mi * 16 + l16) * 64 + (((dk * 4 + quad) ^ (l16 & 7)) * 8)]);
#pragma unroll
    for (int ni = 0; ni < 4; ++ni)
#pragma unroll
      for (int dk = 0; dk < 2; ++dk)
        bfr[ni][dk] = lds_load8(
            &Bl[(wn + ni * 16 + l16) * 64 + (((dk * 4 + quad) ^ (l16 & 7)) * 8)]);
#pragma unroll
    for (int mi = 0; mi < 4; ++mi)
#pragma unroll
      for (int ni = 0; ni < 4; ++ni) {
        acc[mi][ni] = __builtin_amdgcn_mfma_f32_16x16x32_bf16(
            af[mi][0], bfr[ni][0], acc[mi][ni], 0, 0, 0);
        acc[mi][ni] = __builtin_amdgcn_mfma_f32_16x16x32_bf16(
            af[mi][1], bfr[ni][1], acc[mi][ni], 0, 0, 0);
      }
  }

#pragma unroll
  for (int mi = 0; mi < 4; ++mi)
#pragma unroll
    for (int r = 0; r < 4; ++r) {
      int m = m0 + wm + mi * 16 + quad * 4 + r;
#pragma unroll
      for (int ni = 0; ni < 4; ++ni) {
        int c = n0 + wn + ni * 16 + l16;
        out[(size_t)m * 1024 + c] = acc[mi][ni][r] + bp[c];
      }
    }
}

extern "C" void kernel_launch(void* const* d_in, const int* in_sizes, int n_in,
                              void* d_out, int out_size, void* d_ws, size_t ws_size,
                              hipStream_t stream) {
  const float* x      = (const float*)d_in[0];
  const float* W_attn = (const float*)d_in[1];
  const float* b_attn = (const float*)d_in[2];
  const float* W_proj = (const float*)d_in[3];
  const float* b_proj = (const float*)d_in[4];
  const float* bQ     = (const float*)d_in[5];
  const float* bK     = (const float*)d_in[6];
  const float* bV     = (const float*)d_in[7];
  float* out = (float*)d_out;

  unsigned short* xb   = (unsigned short*)d_ws;        // 8,388,608
  unsigned short* Yb   = xb;                           // alias (xb dead after qkv)
  unsigned short* Wt_a = xb + 8388608;                 // 3,145,728
  unsigned short* Wt_p = Wt_a + 3145728;               // 1,048,576
  unsigned short* Qb   = Wt_p + 1048576;               // 8,388,608
  unsigned short* Kb   = Qb + 8388608;
  unsigned short* Vb   = Kb + 8388608;                 // [B,H,D,T]

  prep<<<dim3(4096 + 768 + 256), dim3(256), 0, stream>>>(x, W_attn, W_proj,
                                                         xb, Wt_a, Wt_p);
  qkv_gemm<<<dim3(64 * 24), dim3(256), 0, stream>>>(xb, Wt_a, b_attn, bQ, bK, bV,
                                                    Qb, Kb, Vb);
  attn_kernel<<<dim3(16 * 64), dim3(256), 0, stream>>>(Qb, Kb, Vb, Yb);
  proj_gemm<<<dim3(64 * 8), dim3(256), 0, stream>>>(Yb, Wt_p, b_proj, out);
}